// Round 1
// baseline (1016.710 us; speedup 1.0000x reference)
//
#include <hip/hip_runtime.h>
#include <hip/hip_bf16.h>

typedef float f4 __attribute__((ext_vector_type(4)));
typedef __bf16 bf16x4 __attribute__((ext_vector_type(4)));
typedef __bf16 bf16x8 __attribute__((ext_vector_type(8)));

#define BATCH 16
#define CCH 512
#define HW 4096

// ---------------- per-(b,c) stats: rstd and rstd*mu for f_c and f_s ----------------
__global__ __launch_bounds__(256) void stats_kernel(
    const float* __restrict__ fc, const float* __restrict__ fs,
    float* __restrict__ rstd_c, float* __restrict__ rmu_c,
    float* __restrict__ rstd_s, float* __restrict__ rmu_s)
{
    const int row = blockIdx.x;                       // b*C + c, 0..8191
    const float* src = (blockIdx.y == 0 ? fc : fs) + (size_t)row * HW;
    float s = 0.f, sq = 0.f;
    for (int i = threadIdx.x; i < HW / 4; i += 256) {
        f4 v = ((const f4*)src)[i];
        s  += v[0] + v[1] + v[2] + v[3];
        sq += v[0]*v[0] + v[1]*v[1] + v[2]*v[2] + v[3]*v[3];
    }
    for (int off = 32; off > 0; off >>= 1) {
        s  += __shfl_down(s,  off, 64);
        sq += __shfl_down(sq, off, 64);
    }
    __shared__ float ss[4], ssq[4];
    if ((threadIdx.x & 63) == 0) { ss[threadIdx.x >> 6] = s; ssq[threadIdx.x >> 6] = sq; }
    __syncthreads();
    if (threadIdx.x == 0) {
        float S = ss[0] + ss[1] + ss[2] + ss[3];
        float Q = ssq[0] + ssq[1] + ssq[2] + ssq[3];
        float mu  = S * (1.f / HW);
        float var = Q * (1.f / HW) - mu * mu;
        float r = rsqrtf(var + 1e-5f);
        float* rs = (blockIdx.y == 0) ? rstd_c : rstd_s;
        float* rm = (blockIdx.y == 0) ? rmu_c  : rmu_s;
        rs[row] = r;
        rm[row] = r * mu;
    }
}

// ---------------- weight prep: w1,w2 -> bf16 ; w3 -> transposed bf16 ----------------
__global__ __launch_bounds__(256) void prep_w_kernel(
    const float* __restrict__ w1, const float* __restrict__ w2, const float* __restrict__ w3,
    __bf16* __restrict__ w1b, __bf16* __restrict__ w2b, __bf16* __restrict__ w3t)
{
    int i = blockIdx.x * 256 + threadIdx.x;           // 0..262143
    int z = blockIdx.y;
    if (z == 0)      w1b[i] = (__bf16)w1[i];
    else if (z == 1) w2b[i] = (__bf16)w2[i];
    else             w3t[i] = (__bf16)w3[(i & 511) * 512 + (i >> 9)];  // w3t[e][d] = w3[d][e]
}

// ---------------- v[b*C+c] = sum_d attn[b][c][d] * b3[d] ----------------
__global__ __launch_bounds__(256) void v_kernel(
    const __bf16* __restrict__ attn, const float* __restrict__ b3, float* __restrict__ v)
{
    const int row = blockIdx.x;                       // 0..8191
    const __bf16* ar = attn + (size_t)row * CCH;
    float s = 0.f;
    for (int i = threadIdx.x; i < CCH; i += 256) s += (float)ar[i] * b3[i];
    for (int off = 32; off > 0; off >>= 1) s += __shfl_down(s, off, 64);
    __shared__ float ss[4];
    if ((threadIdx.x & 63) == 0) ss[threadIdx.x >> 6] = s;
    __syncthreads();
    if (threadIdx.x == 0) v[row] = ss[0] + ss[1] + ss[2] + ss[3];
}

// ---------------- generic batched GEMM:  D[b][i][j] = sum_k A[b][i][k] * Bm[b][j][k] ----------------
// B_KMAJOR: B stored [N][K] (NT, K contiguous).  !B_KMAJOR: B stored [K][N] (NN), fp32 only.
// Epilogue: val = acc * s1[row] * s2[col] + tscale * t1[row] * t2[col]   (null ptr => 1 for s/t2, skip for t1)
template<bool A_F32, bool B_F32, bool B_KMAJOR, bool D_F32>
__global__ __launch_bounds__(256) void gemm_kernel(
    const void* __restrict__ Ap, const void* __restrict__ Bp, void* __restrict__ Dp,
    int K, int lda, int ldb, int ldd,
    long long sA, long long sB, long long sD,
    const float* __restrict__ s1, int vs1, const float* __restrict__ s2, int vs2,
    const float* __restrict__ t1, int vt1, const float* __restrict__ t2, int vt2,
    float tscale)
{
    static_assert(B_F32 || B_KMAJOR, "NN staging only implemented for fp32 B");
    constexpr int BM = 128, BN = 128, BK = 32, LS = BK + 8;  // LS=40 -> 80B rows, 16B-aligned, 2-way banks
    __shared__ __bf16 As[BM * LS];
    __shared__ __bf16 Bs[BN * LS];

    const int tid = threadIdx.x;
    const int m0 = blockIdx.y * BM, n0 = blockIdx.x * BN;
    const int b = blockIdx.z;
    const int lane = tid & 63, wid = tid >> 6;
    const int wm = (wid >> 1) * 64, wn = (wid & 1) * 64;
    const int l16 = lane & 15, l4 = lane >> 4;

    const char* Abase = (const char*)Ap + (long long)b * sA * (A_F32 ? 4 : 2);
    const char* Bbase = (const char*)Bp + (long long)b * sB * (B_F32 ? 4 : 2);
    char* Dbase = (char*)Dp + (long long)b * sD * (D_F32 ? 4 : 2);

    f4 acc[4][4];
    #pragma unroll
    for (int i = 0; i < 4; i++)
        #pragma unroll
        for (int j = 0; j < 4; j++) acc[i][j] = (f4){0.f, 0.f, 0.f, 0.f};

    for (int kt = 0; kt < K; kt += BK) {
        __syncthreads();
        // ---- stage A tile (BM x BK) -> As[m][k] ----
        if (A_F32) {
            const float* A32 = (const float*)Abase;
            #pragma unroll
            for (int q = tid; q < BM * BK / 4; q += 256) {
                int r = q >> 3, c = (q & 7) * 4;
                f4 v = *(const f4*)(A32 + (size_t)(m0 + r) * lda + kt + c);
                bf16x4 o;
                o[0] = (__bf16)v[0]; o[1] = (__bf16)v[1]; o[2] = (__bf16)v[2]; o[3] = (__bf16)v[3];
                *(bf16x4*)&As[r * LS + c] = o;
            }
        } else {
            const __bf16* A16 = (const __bf16*)Abase;
            #pragma unroll
            for (int q = tid; q < BM * BK / 8; q += 256) {
                int r = q >> 2, c = (q & 3) * 8;
                *(bf16x8*)&As[r * LS + c] = *(const bf16x8*)(A16 + (size_t)(m0 + r) * lda + kt + c);
            }
        }
        // ---- stage B tile -> Bs[n][k] ----
        if (B_KMAJOR) {
            if (B_F32) {
                const float* B32 = (const float*)Bbase;
                #pragma unroll
                for (int q = tid; q < BN * BK / 4; q += 256) {
                    int r = q >> 3, c = (q & 7) * 4;
                    f4 v = *(const f4*)(B32 + (size_t)(n0 + r) * ldb + kt + c);
                    bf16x4 o;
                    o[0] = (__bf16)v[0]; o[1] = (__bf16)v[1]; o[2] = (__bf16)v[2]; o[3] = (__bf16)v[3];
                    *(bf16x4*)&Bs[r * LS + c] = o;
                }
            } else {
                const __bf16* B16 = (const __bf16*)Bbase;
                #pragma unroll
                for (int q = tid; q < BN * BK / 8; q += 256) {
                    int r = q >> 2, c = (q & 3) * 8;
                    *(bf16x8*)&Bs[r * LS + c] = *(const bf16x8*)(B16 + (size_t)(n0 + r) * ldb + kt + c);
                }
            }
        } else {
            // B is [K][N] fp32 (f_s): coalesced read along N, transpose into Bs[n][k]
            const float* B32 = (const float*)Bbase;
            #pragma unroll
            for (int q = tid; q < BK * BN / 4; q += 256) {
                int k = q >> 5, c = (q & 31) * 4;
                f4 v = *(const f4*)(B32 + (size_t)(kt + k) * ldb + n0 + c);
                Bs[(c + 0) * LS + k] = (__bf16)v[0];
                Bs[(c + 1) * LS + k] = (__bf16)v[1];
                Bs[(c + 2) * LS + k] = (__bf16)v[2];
                Bs[(c + 3) * LS + k] = (__bf16)v[3];
            }
        }
        __syncthreads();

        bf16x8 af[4], bf[4];
        #pragma unroll
        for (int i = 0; i < 4; i++)
            af[i] = *(const bf16x8*)&As[(wm + i * 16 + l16) * LS + l4 * 8];
        #pragma unroll
        for (int i = 0; i < 4; i++)
            bf[i] = *(const bf16x8*)&Bs[(wn + i * 16 + l16) * LS + l4 * 8];
        #pragma unroll
        for (int i = 0; i < 4; i++)
            #pragma unroll
            for (int j = 0; j < 4; j++)
                acc[i][j] = __builtin_amdgcn_mfma_f32_16x16x32_bf16(af[i], bf[j], acc[i][j], 0, 0, 0);
    }

    // ---- epilogue ----
    const float* s1b = s1 ? s1 + (long long)b * vs1 : nullptr;
    const float* s2b = s2 ? s2 + (long long)b * vs2 : nullptr;
    const float* t1b = t1 ? t1 + (long long)b * vt1 : nullptr;
    const float* t2b = t2 ? t2 + (long long)b * vt2 : nullptr;

    #pragma unroll
    for (int j = 0; j < 4; j++) {
        int col = n0 + wn + j * 16 + l16;
        float cs = s2b ? s2b[col] : 1.f;
        float ct = t2b ? t2b[col] : 1.f;
        #pragma unroll
        for (int i = 0; i < 4; i++) {
            #pragma unroll
            for (int r = 0; r < 4; r++) {
                int row = m0 + wm + i * 16 + l4 * 4 + r;
                float val = acc[i][j][r];
                if (s1b) val *= s1b[row];
                val *= cs;
                if (t1b) val += tscale * t1b[row] * ct;
                size_t idx = (size_t)row * ldd + col;
                if (D_F32) ((float*)Dbase)[idx] = val;
                else       ((__bf16*)Dbase)[idx] = (__bf16)val;
            }
        }
    }
}

extern "C" void kernel_launch(void* const* d_in, const int* in_sizes, int n_in,
                              void* d_out, int out_size, void* d_ws, size_t ws_size,
                              hipStream_t stream) {
    (void)in_sizes; (void)n_in; (void)out_size; (void)ws_size;
    const float* f_c = (const float*)d_in[0];
    const float* f_s = (const float*)d_in[1];
    const float* w1  = (const float*)d_in[2];
    const float* b1  = (const float*)d_in[3];
    const float* w2  = (const float*)d_in[4];
    const float* b2  = (const float*)d_in[5];
    const float* w3  = (const float*)d_in[6];
    const float* b3  = (const float*)d_in[7];
    float* out = (float*)d_out;

    // workspace layout (needs ~33.7 MB)
    char* ws = (char*)d_ws;
    float*  rstd_c = (float*)(ws + 0);
    float*  rmu_c  = (float*)(ws + 32768);
    float*  rstd_s = (float*)(ws + 65536);
    float*  rmu_s  = (float*)(ws + 98304);
    float*  vvec   = (float*)(ws + 131072);
    __bf16* w1b    = (__bf16*)(ws + 163840);
    __bf16* w2b    = (__bf16*)(ws + 688128);
    __bf16* w3t    = (__bf16*)(ws + 1212416);
    __bf16* G      = (__bf16*)(ws + 1736704);    // 16 x 512 x 512 bf16
    __bf16* Tt     = (__bf16*)(ws + 10125312);
    __bf16* attn   = (__bf16*)(ws + 18513920);
    __bf16* Mbuf   = (__bf16*)(ws + 26902528);

    const long long sBig = (long long)CCH * HW;   // 512*4096
    const long long sSm  = (long long)CCH * CCH;  // 512*512

    // 1. stats for f_c, f_s
    stats_kernel<<<dim3(BATCH * CCH, 2), 256, 0, stream>>>(f_c, f_s, rstd_c, rmu_c, rstd_s, rmu_s);
    // 2. weight prep
    prep_w_kernel<<<dim3(1024, 3), 256, 0, stream>>>(w1, w2, w3, w1b, w2b, w3t);
    // 3. Gram: G[b][c][d] = rs_s[c]*rs_c[d]*( f_s[b,c,:].f_c[b,d,:] - 4096*mu_s[c]*mu_c[d] )
    gemm_kernel<true, true, true, false><<<dim3(4, 4, BATCH), 256, 0, stream>>>(
        f_s, f_c, G, HW, HW, HW, CCH, sBig, sBig, sSm,
        rstd_s, CCH, rstd_c, CCH, rmu_s, CCH, rmu_c, CCH, -4096.f);
    // 4. Tt[b][e][d] = sum_x w1[e,x] * G[b][d,x]   (= (G@w1^T)^T)
    gemm_kernel<false, false, true, false><<<dim3(4, 4, BATCH), 256, 0, stream>>>(
        w1b, G, Tt, CCH, CCH, CCH, CCH, 0LL, sSm, sSm,
        nullptr, 0, nullptr, 0, nullptr, 0, nullptr, 0, 0.f);
    // 5. attn[b][c][e] = sum_d w2[c,d] * Tt[b][e,d] + 4096*b2[c]*b1[e]
    gemm_kernel<false, false, true, false><<<dim3(4, 4, BATCH), 256, 0, stream>>>(
        w2b, Tt, attn, CCH, CCH, CCH, CCH, 0LL, sSm, sSm,
        nullptr, 0, nullptr, 0, b2, 0, b1, 0, 4096.f);
    // 6. v[b][c] = attn[b][c,:] . b3
    v_kernel<<<dim3(BATCH * CCH), 256, 0, stream>>>(attn, b3, vvec);
    // 7. M[b][c][e] = sum_d attn[b][c,d] * w3t[e,d]   (= attn @ w3)
    gemm_kernel<false, false, true, false><<<dim3(4, 4, BATCH), 256, 0, stream>>>(
        attn, w3t, Mbuf, CCH, CCH, CCH, CCH, sSm, 0LL, sSm,
        nullptr, 0, nullptr, 0, nullptr, 0, nullptr, 0, 0.f);
    // 8. out[b][c][n] = sum_e M[b][c,e] * f_s[b][e,n] + v[b][c]   (B in [K][N] layout)
    gemm_kernel<false, true, false, true><<<dim3(32, 4, BATCH), 256, 0, stream>>>(
        Mbuf, f_s, out, CCH, CCH, HW, HW, sSm, sBig, sBig,
        nullptr, 0, nullptr, 0, vvec, CCH, nullptr, 0, 1.f);
}

// Round 2
// 626.017 us; speedup vs baseline: 1.6241x; 1.6241x over previous
//
#include <hip/hip_runtime.h>
#include <hip/hip_bf16.h>

typedef float f4 __attribute__((ext_vector_type(4)));
typedef __bf16 bf16x4 __attribute__((ext_vector_type(4)));
typedef __bf16 bf16x8 __attribute__((ext_vector_type(8)));

#define BATCH 16
#define CCH 512
#define HW 4096

// ---------- fused stats + fp32->bf16 conversion (dst may be null) ----------
__global__ __launch_bounds__(256) void stats_conv_kernel(
    const float* __restrict__ fc, const float* __restrict__ fs,
    __bf16* __restrict__ fcb, __bf16* __restrict__ fsb,
    float* __restrict__ rstd_c, float* __restrict__ rmu_c,
    float* __restrict__ rstd_s, float* __restrict__ rmu_s)
{
    const int row = blockIdx.x;
    const bool is_c = (blockIdx.y == 0);
    const float* src = (is_c ? fc : fs) + (size_t)row * HW;
    __bf16* dst = is_c ? fcb : fsb;
    float s = 0.f, sq = 0.f;
    for (int i = threadIdx.x; i < HW / 4; i += 256) {
        f4 v = ((const f4*)src)[i];
        s  += v[0] + v[1] + v[2] + v[3];
        sq += v[0]*v[0] + v[1]*v[1] + v[2]*v[2] + v[3]*v[3];
        if (dst) {
            bf16x4 o;
            o[0] = (__bf16)v[0]; o[1] = (__bf16)v[1]; o[2] = (__bf16)v[2]; o[3] = (__bf16)v[3];
            *(bf16x4*)(dst + (size_t)row * HW + i * 4) = o;
        }
    }
    for (int off = 32; off > 0; off >>= 1) {
        s  += __shfl_down(s,  off, 64);
        sq += __shfl_down(sq, off, 64);
    }
    __shared__ float ss[4], ssq[4];
    if ((threadIdx.x & 63) == 0) { ss[threadIdx.x >> 6] = s; ssq[threadIdx.x >> 6] = sq; }
    __syncthreads();
    if (threadIdx.x == 0) {
        float S = ss[0] + ss[1] + ss[2] + ss[3];
        float Q = ssq[0] + ssq[1] + ssq[2] + ssq[3];
        float mu  = S * (1.f / HW);
        float var = Q * (1.f / HW) - mu * mu;
        float r = rsqrtf(var + 1e-5f);
        (is_c ? rstd_c : rstd_s)[row] = r;
        (is_c ? rmu_c  : rmu_s )[row] = r * mu;
    }
}

// ---------- weight prep: w2 -> bf16; w1,w3 -> transposed bf16 ----------
__global__ __launch_bounds__(256) void prep_w_kernel(
    const float* __restrict__ w1, const float* __restrict__ w2, const float* __restrict__ w3,
    __bf16* __restrict__ w1t, __bf16* __restrict__ w2b, __bf16* __restrict__ w3t)
{
    int i = blockIdx.x * 256 + threadIdx.x;
    int z = blockIdx.y;
    if (z == 0)      w2b[i] = (__bf16)w2[i];
    else if (z == 1) w3t[i] = (__bf16)w3[(i & 511) * 512 + (i >> 9)];
    else             w1t[i] = (__bf16)w1[(i & 511) * 512 + (i >> 9)];
}

// ---------- u1[d] = sum_x w1[x,d]*b3[x] ; bw3[d] = sum_x w3[x,d]*b1[x] ----------
__global__ __launch_bounds__(256) void u_kernel(
    const float* __restrict__ w1, const float* __restrict__ b3,
    const float* __restrict__ w3, const float* __restrict__ b1,
    float* __restrict__ u1, float* __restrict__ bw3)
{
    int d = blockIdx.x * 256 + threadIdx.x;        // grid (2, 2)
    const float* W = blockIdx.y == 0 ? w1 : w3;
    const float* v = blockIdx.y == 0 ? b3 : b1;
    float* o       = blockIdx.y == 0 ? u1 : bw3;
    float s = 0.f;
    for (int x = 0; x < 512; x++) s += W[x * 512 + d] * v[x];
    o[d] = s;
}

__global__ __launch_bounds__(256) void b1b3_kernel(
    const float* __restrict__ b1, const float* __restrict__ b3, float* __restrict__ o)
{
    int t = threadIdx.x;
    float s = b1[t] * b3[t] + b1[t + 256] * b3[t + 256];
    for (int off = 32; off > 0; off >>= 1) s += __shfl_down(s, off, 64);
    __shared__ float ss[4];
    if ((t & 63) == 0) ss[t >> 6] = s;
    __syncthreads();
    if (t == 0) o[0] = ss[0] + ss[1] + ss[2] + ss[3];
}

// ---------- Gram epilogue: G = bf16( rs_s*rs_c*Graw - 4096*rmu_s*rmu_c ) ----------
__global__ __launch_bounds__(256) void gram_epi_kernel(
    const float* __restrict__ Graw, __bf16* __restrict__ G,
    const float* __restrict__ rstd_s, const float* __restrict__ rmu_s,
    const float* __restrict__ rstd_c, const float* __restrict__ rmu_c)
{
    size_t i4 = (size_t)blockIdx.x * 256 + threadIdx.x;
    size_t flat = i4 * 4;
    int b  = (int)(flat >> 18);
    int c  = (int)((flat >> 9) & 511);
    int d0 = (int)(flat & 511);
    float rs = rstd_s[b * 512 + c], rm = rmu_s[b * 512 + c];
    f4 g = *(const f4*)(Graw + flat);
    bf16x4 o;
    #pragma unroll
    for (int t = 0; t < 4; t++) {
        float val = rs * rstd_c[b * 512 + d0 + t] * g[t]
                  - 4096.f * rm * rmu_c[b * 512 + d0 + t];
        o[t] = (__bf16)val;
    }
    *(bf16x4*)(G + flat) = o;
}

// ---------- q[b,x] = sum_d G[b,x,d]*u1[d] ----------
__global__ __launch_bounds__(64) void q_kernel(
    const __bf16* __restrict__ G, const float* __restrict__ u1, float* __restrict__ q)
{
    int r = blockIdx.x;
    const __bf16* row = G + (size_t)r * 512;
    float s = 0.f;
    for (int i = threadIdx.x; i < 512; i += 64) s += (float)row[i] * u1[i];
    for (int off = 32; off > 0; off >>= 1) s += __shfl_down(s, off, 64);
    if (threadIdx.x == 0) q[r] = s;
}

// ---------- v[b,c] = sum_x w2[c,x]*q[b,x] + 4096*(b1.b3)*b2[c] ----------
__global__ __launch_bounds__(64) void v2_kernel(
    const float* __restrict__ w2, const float* __restrict__ qv,
    const float* __restrict__ b2, const float* __restrict__ b1b3,
    float* __restrict__ vv)
{
    int r = blockIdx.x, b = r >> 9, c = r & 511;
    float s = 0.f;
    for (int i = threadIdx.x; i < 512; i += 64) s += w2[c * 512 + i] * qv[b * 512 + i];
    for (int off = 32; off > 0; off >>= 1) s += __shfl_down(s, off, 64);
    if (threadIdx.x == 0) vv[r] = s + 4096.f * b1b3[0] * b2[c];
}

// ---------- generic batched GEMM: D[b][i][j] = sum_k A[b][i][k] * B'[...] ----------
// B_KMAJOR: B stored [N][K] (NT). !B_KMAJOR: B stored [K][N] (NN), BN must be 128.
// ATOMIC: fp32 atomicAdd into D (split-K), no epilogue scaling.
// Epilogue (non-atomic): val = acc*s1[row]*s2[col] + tscale*t1[row]*t2[col]
template<int BM, int BN, bool A_F32, bool B_F32, bool B_KMAJOR, bool D_F32, bool ATOMIC>
__global__ __launch_bounds__(256) void gemm_kernel(
    const void* __restrict__ Ap, const void* __restrict__ Bp, void* __restrict__ Dp,
    int K, int splitk, int lda, int ldb, int ldd,
    long long sA, long long sB, long long sD,
    const float* __restrict__ s1, int vs1, const float* __restrict__ s2, int vs2,
    const float* __restrict__ t1, int vt1, const float* __restrict__ t2, int vt2,
    float tscale)
{
    static_assert(B_KMAJOR || BN == 128, "NN staging assumes BN=128");
    constexpr int FM = BM / 32, FN = BN / 32;
    constexpr int LSA = 40;                       // halfwords; 80B rows, 16B-aligned
    constexpr int LSB = B_KMAJOR ? 40 : 36;       // NN: 72B rows, b64-aligned, odd*2-word stride
    __shared__ __bf16 As[BM * LSA];
    __shared__ __bf16 Bs[BN * LSB];

    const int tid = threadIdx.x;
    const int b = blockIdx.z / splitk;
    const int chunk = blockIdx.z % splitk;
    const int klen = K / splitk;
    const int k0 = chunk * klen, k1 = k0 + klen;
    const int m0 = blockIdx.y * BM, n0 = blockIdx.x * BN;
    const int lane = tid & 63, wid = tid >> 6;
    const int wm = (wid >> 1) * (BM / 2), wn = (wid & 1) * (BN / 2);
    const int l16 = lane & 15, l4 = lane >> 4;

    const char* Abase = (const char*)Ap + (long long)b * sA * (A_F32 ? 4 : 2);
    const char* Bbase = (const char*)Bp + (long long)b * sB * (B_F32 ? 4 : 2);
    char* Dbase = (char*)Dp + (long long)b * sD * (D_F32 ? 4 : 2);

    f4 acc[FM][FN];
    #pragma unroll
    for (int i = 0; i < FM; i++)
        #pragma unroll
        for (int j = 0; j < FN; j++) acc[i][j] = (f4){0.f, 0.f, 0.f, 0.f};

    for (int kt = k0; kt < k1; kt += 32) {
        __syncthreads();
        // ---- stage A (BM x 32, K-major) ----
        if (A_F32) {
            const float* A32 = (const float*)Abase;
            #pragma unroll
            for (int it = 0; it < BM / 32; it++) {
                int q = it * 256 + tid;
                int r = q >> 3, c = (q & 7) * 4;
                f4 v = *(const f4*)(A32 + (size_t)(m0 + r) * lda + kt + c);
                bf16x4 o;
                o[0] = (__bf16)v[0]; o[1] = (__bf16)v[1]; o[2] = (__bf16)v[2]; o[3] = (__bf16)v[3];
                *(bf16x4*)&As[r * LSA + c] = o;
            }
        } else {
            const __bf16* A16 = (const __bf16*)Abase;
            #pragma unroll
            for (int it = 0; it < BM / 64; it++) {
                int q = it * 256 + tid;
                int r = q >> 2, c = (q & 3) * 8;
                *(bf16x8*)&As[r * LSA + c] = *(const bf16x8*)(A16 + (size_t)(m0 + r) * lda + kt + c);
            }
        }
        // ---- stage B ----
        if (B_KMAJOR) {
            if (B_F32) {
                const float* B32 = (const float*)Bbase;
                #pragma unroll
                for (int it = 0; it < BN / 32; it++) {
                    int q = it * 256 + tid;
                    int r = q >> 3, c = (q & 7) * 4;
                    f4 v = *(const f4*)(B32 + (size_t)(n0 + r) * ldb + kt + c);
                    bf16x4 o;
                    o[0] = (__bf16)v[0]; o[1] = (__bf16)v[1]; o[2] = (__bf16)v[2]; o[3] = (__bf16)v[3];
                    *(bf16x4*)&Bs[r * LSB + c] = o;
                }
            } else {
                const __bf16* B16 = (const __bf16*)Bbase;
                #pragma unroll
                for (int it = 0; it < BN / 64; it++) {
                    int q = it * 256 + tid;
                    int r = q >> 2, c = (q & 3) * 8;
                    *(bf16x8*)&Bs[r * LSB + c] = *(const bf16x8*)(B16 + (size_t)(n0 + r) * ldb + kt + c);
                }
            }
        } else {
            // B is [K][N]: transpose-stage. Thread owns 4 consecutive k for one n,
            // writes ONE contiguous b64 -> conflict-light (72B row pitch).
            const int n = tid & 127;
            const int kh = (tid >> 7) * 4;        // 0 or 4
            #pragma unroll
            for (int kk = 0; kk < 32; kk += 8) {
                int k = kk + kh;
                bf16x4 o;
                if (B_F32) {
                    const float* B32 = (const float*)Bbase;
                    #pragma unroll
                    for (int t = 0; t < 4; t++)
                        o[t] = (__bf16)B32[(size_t)(kt + k + t) * ldb + n0 + n];
                } else {
                    const __bf16* B16 = (const __bf16*)Bbase;
                    #pragma unroll
                    for (int t = 0; t < 4; t++)
                        o[t] = B16[(size_t)(kt + k + t) * ldb + n0 + n];
                }
                *(bf16x4*)&Bs[n * LSB + k] = o;
            }
        }
        __syncthreads();

        bf16x8 af[FM], bfr[FN];
        #pragma unroll
        for (int i = 0; i < FM; i++)
            af[i] = *(const bf16x8*)&As[(wm + i * 16 + l16) * LSA + l4 * 8];
        #pragma unroll
        for (int j = 0; j < FN; j++) {
            if (B_KMAJOR) {
                bfr[j] = *(const bf16x8*)&Bs[(wn + j * 16 + l16) * LSB + l4 * 8];
            } else {
                const __bf16* p = &Bs[(wn + j * 16 + l16) * LSB + l4 * 8];
                bf16x4 lo = *(const bf16x4*)p;
                bf16x4 hi = *(const bf16x4*)(p + 4);
                bf16x8 r;
                r[0]=lo[0]; r[1]=lo[1]; r[2]=lo[2]; r[3]=lo[3];
                r[4]=hi[0]; r[5]=hi[1]; r[6]=hi[2]; r[7]=hi[3];
                bfr[j] = r;
            }
        }
        #pragma unroll
        for (int i = 0; i < FM; i++)
            #pragma unroll
            for (int j = 0; j < FN; j++)
                acc[i][j] = __builtin_amdgcn_mfma_f32_16x16x32_bf16(af[i], bfr[j], acc[i][j], 0, 0, 0);
    }

    // ---- epilogue ----
    if (ATOMIC) {
        float* D32 = (float*)Dbase;
        #pragma unroll
        for (int j = 0; j < FN; j++) {
            int col = n0 + wn + j * 16 + l16;
            #pragma unroll
            for (int i = 0; i < FM; i++)
                #pragma unroll
                for (int rr = 0; rr < 4; rr++) {
                    int row = m0 + wm + i * 16 + l4 * 4 + rr;
                    atomicAdd(D32 + (size_t)row * ldd + col, acc[i][j][rr]);
                }
        }
        return;
    }
    const float* s1b = s1 ? s1 + (long long)b * vs1 : nullptr;
    const float* s2b = s2 ? s2 + (long long)b * vs2 : nullptr;
    const float* t1b = t1 ? t1 + (long long)b * vt1 : nullptr;
    const float* t2b = t2 ? t2 + (long long)b * vt2 : nullptr;
    #pragma unroll
    for (int j = 0; j < FN; j++) {
        int col = n0 + wn + j * 16 + l16;
        float cs = s2b ? s2b[col] : 1.f;
        float ct = t2b ? t2b[col] : 1.f;
        #pragma unroll
        for (int i = 0; i < FM; i++) {
            #pragma unroll
            for (int rr = 0; rr < 4; rr++) {
                int row = m0 + wm + i * 16 + l4 * 4 + rr;
                float val = acc[i][j][rr];
                if (s1b) val *= s1b[row];
                val *= cs;
                if (t1b) val += tscale * t1b[row] * ct;
                size_t idx = (size_t)row * ldd + col;
                if (D_F32) ((float*)Dbase)[idx] = val;
                else       ((__bf16*)Dbase)[idx] = (__bf16)val;
            }
        }
    }
}

extern "C" void kernel_launch(void* const* d_in, const int* in_sizes, int n_in,
                              void* d_out, int out_size, void* d_ws, size_t ws_size,
                              hipStream_t stream) {
    (void)in_sizes; (void)n_in; (void)out_size;
    const float* f_c = (const float*)d_in[0];
    const float* f_s = (const float*)d_in[1];
    const float* w1  = (const float*)d_in[2];
    const float* b1  = (const float*)d_in[3];
    const float* w2  = (const float*)d_in[4];
    const float* b2  = (const float*)d_in[5];
    const float* w3  = (const float*)d_in[6];
    const float* b3  = (const float*)d_in[7];
    float* out = (float*)d_out;

    char* ws = (char*)d_ws;
    float*  rstd_c = (float*)(ws + 0);
    float*  rmu_c  = (float*)(ws + 32768);
    float*  rstd_s = (float*)(ws + 65536);
    float*  rmu_s  = (float*)(ws + 98304);
    float*  vvec   = (float*)(ws + 131072);
    float*  qvec   = (float*)(ws + 163840);
    float*  u1     = (float*)(ws + 196608);
    float*  bw3    = (float*)(ws + 198656);
    float*  b1b3p  = (float*)(ws + 200704);
    __bf16* w2b    = (__bf16*)(ws + 262144);
    __bf16* w1t    = (__bf16*)(ws + 786432);
    __bf16* w3t    = (__bf16*)(ws + 1310720);
    __bf16* w13t   = (__bf16*)(ws + 1835008);
    float*  Graw   = (float*)(ws + 2359296);          // 16.8 MB, dead after gram_epi
    __bf16* Pt     = (__bf16*)(ws + 2359296);         // aliases Graw[0 : 8.4MB]
    __bf16* Mbuf   = (__bf16*)(ws + 10747904);        // aliases Graw[8.4 : 16.8MB]
    __bf16* G      = (__bf16*)(ws + 19136512);        // 8.4 MB -> core ends at 27.5 MB
    __bf16* fcb    = (__bf16*)(ws + 27525120);        // 67 MB
    __bf16* fsb    = (__bf16*)(ws + 94633984);        // 67 MB -> 161.7 MB
    const bool CONV = ws_size >= (size_t)161742848;

    const long long sBig = (long long)CCH * HW;
    const long long sSm  = (long long)CCH * CCH;

    stats_conv_kernel<<<dim3(BATCH * CCH, 2), 256, 0, stream>>>(
        f_c, f_s, CONV ? fcb : nullptr, CONV ? fsb : nullptr,
        rstd_c, rmu_c, rstd_s, rmu_s);
    prep_w_kernel<<<dim3(1024, 3), 256, 0, stream>>>(w1, w2, w3, w1t, w2b, w3t);
    u_kernel<<<dim3(2, 2), 256, 0, stream>>>(w1, b3, w3, b1, u1, bw3);
    b1b3_kernel<<<1, 256, 0, stream>>>(b1, b3, b1b3p);
    (void)hipMemsetAsync(Graw, 0, (size_t)16777216, stream);

    // Gram (split-K=4, atomic fp32): Graw[b][c][d] = f_s[b,c,:].f_c[b,d,:]
    if (CONV)
        gemm_kernel<128,128,false,false,true,true,true><<<dim3(4, 4, BATCH * 4), 256, 0, stream>>>(
            fsb, fcb, Graw, HW, 4, HW, HW, CCH, sBig, sBig, sSm,
            nullptr,0, nullptr,0, nullptr,0, nullptr,0, 0.f);
    else
        gemm_kernel<128,128,true,true,true,true,true><<<dim3(4, 4, BATCH * 4), 256, 0, stream>>>(
            f_s, f_c, Graw, HW, 4, HW, HW, CCH, sBig, sBig, sSm,
            nullptr,0, nullptr,0, nullptr,0, nullptr,0, 0.f);
    gram_epi_kernel<<<4096, 256, 0, stream>>>(Graw, G, rstd_s, rmu_s, rstd_c, rmu_c);

    // w13t[e][d] = sum_x w3[x,e]*w1[x,d]  (batch-independent)
    gemm_kernel<64,64,false,false,true,false,false><<<dim3(8, 8, 1), 256, 0, stream>>>(
        w3t, w1t, w13t, CCH, 1, CCH, CCH, CCH, 0, 0, 0,
        nullptr,0, nullptr,0, nullptr,0, nullptr,0, 0.f);
    // Pt[b][e][x] = sum_d w13t[e,d]*G[b][x,d]
    gemm_kernel<64,64,false,false,true,false,false><<<dim3(8, 8, BATCH), 256, 0, stream>>>(
        w13t, G, Pt, CCH, 1, CCH, CCH, CCH, 0, sSm, sSm,
        nullptr,0, nullptr,0, nullptr,0, nullptr,0, 0.f);
    // M[b][c][e] = sum_x w2[c,x]*Pt[b][e,x] + 4096*b2[c]*bw3[e]
    gemm_kernel<64,64,false,false,true,false,false><<<dim3(8, 8, BATCH), 256, 0, stream>>>(
        w2b, Pt, Mbuf, CCH, 1, CCH, CCH, CCH, 0, sSm, sSm,
        nullptr,0, nullptr,0, b2,0, bw3,0, 4096.f);

    q_kernel<<<BATCH * CCH, 64, 0, stream>>>(G, u1, qvec);
    v2_kernel<<<BATCH * CCH, 64, 0, stream>>>(w2, qvec, b2, b1b3p, vvec);

    // out[b][c][n] = sum_e M[b][c,e]*f_s[b][e,n] + v[b][c]
    if (CONV)
        gemm_kernel<128,128,false,false,false,true,false><<<dim3(32, 4, BATCH), 256, 0, stream>>>(
            Mbuf, fsb, out, CCH, 1, CCH, HW, HW, sSm, sBig, sBig,
            nullptr,0, nullptr,0, vvec,CCH, nullptr,0, 1.f);
    else
        gemm_kernel<128,128,false,true,false,true,false><<<dim3(32, 4, BATCH), 256, 0, stream>>>(
            Mbuf, f_s, out, CCH, 1, CCH, HW, HW, sSm, sBig, sBig,
            nullptr,0, nullptr,0, vvec,CCH, nullptr,0, 1.f);
}